// Round 1
// baseline (736.296 us; speedup 1.0000x reference)
//
#include <hip/hip_runtime.h>
#include <cstdint>

// EdgeMLP: out[e] = relu(concat(h[src],h[dst]) @ W1 + b1) @ W2 + b2
// Round 1: fp32 register-tiled baseline (no fp32 MFMA on CDNA4).
// Block = 256 threads, tile = 64 edges. W1 staged in LDS once per block.

constexpr int EMB    = 64;
constexpr int IN_DIM = 128;
constexpr int HID    = 128;
constexpr int BE     = 64;    // edges per tile
constexpr int XPAD   = 132;   // row stride for X tile (16B-aligned rows, balanced banks)

__global__ __launch_bounds__(256, 1)
void edge_mlp_f32(const float* __restrict__ h,
                  const int*   __restrict__ eidx,
                  const float* __restrict__ W1,
                  const float* __restrict__ b1,
                  const float* __restrict__ W2,
                  const float* __restrict__ b2,
                  float* __restrict__ out,
                  int E, int nTiles)
{
    __shared__ float W1s[IN_DIM * HID];   // 64 KB, [k][j]
    __shared__ float Xs[BE * XPAD];       // 33.8 KB, [e][k]

    const int t = threadIdx.x;

    // Stage W1 into LDS (once per block; coalesced float4)
    {
        const float4* src = reinterpret_cast<const float4*>(W1);
        float4*       dst = reinterpret_cast<float4*>(W1s);
        #pragma unroll
        for (int i = 0; i < 16; ++i) dst[i * 256 + t] = src[i * 256 + t];
    }

    // Thread tile: 4 edges x 8 hidden units
    const int tc = t & 15;     // hidden group -> j0
    const int tr = t >> 4;     // edge group   -> e0
    const int j0 = tc * 8;
    const int e0 = tr * 4;

    // Per-thread epilogue constants (L1-cached global reads, once per block)
    float b1r[8], w2a[8], w2b[8];
    #pragma unroll
    for (int j = 0; j < 8; ++j) {
        b1r[j] = b1[j0 + j];
        w2a[j] = W2[(j0 + j) * 2 + 0];
        w2b[j] = W2[(j0 + j) * 2 + 1];
    }
    const float bb0 = b2[0], bb1 = b2[1];

    // Gather mapping: 4 threads per edge, 32 floats each
    const int el   = t >> 2;
    const int part = t & 3;    // 0,1 -> src halves; 2,3 -> dst halves

    for (int tile = blockIdx.x; tile < nTiles; tile += gridDim.x) {
        __syncthreads();   // protect Xs reuse across tiles

        // ---- Gather: X[e] = concat(h[src[e]], h[dst[e]]) ----
        {
            const int eg = tile * BE + el;
            float4 v[8];
            if (eg < E) {
                const int node = (part < 2) ? eidx[eg] : eidx[E + eg];
                const float4* hp = reinterpret_cast<const float4*>(
                    h + (size_t)node * EMB + (size_t)(part & 1) * 32);
                #pragma unroll
                for (int i = 0; i < 8; ++i) v[i] = hp[i];
            } else {
                #pragma unroll
                for (int i = 0; i < 8; ++i) v[i] = make_float4(0.f, 0.f, 0.f, 0.f);
            }
            float4* xrow = reinterpret_cast<float4*>(&Xs[el * XPAD + part * 32]);
            #pragma unroll
            for (int i = 0; i < 8; ++i) xrow[i] = v[i];
        }
        __syncthreads();

        // ---- Layer 1: acc[4e][8j] = X @ W1 ----
        float acc[4][8];
        #pragma unroll
        for (int i = 0; i < 4; ++i)
            #pragma unroll
            for (int j = 0; j < 8; ++j) acc[i][j] = 0.f;

        #pragma unroll 4
        for (int k = 0; k < IN_DIM; ++k) {
            const float4 wa = *reinterpret_cast<const float4*>(&W1s[k * HID + j0]);
            const float4 wb = *reinterpret_cast<const float4*>(&W1s[k * HID + j0 + 4]);
            float xv[4];
            #pragma unroll
            for (int i = 0; i < 4; ++i) xv[i] = Xs[(e0 + i) * XPAD + k];
            #pragma unroll
            for (int i = 0; i < 4; ++i) {
                acc[i][0] = fmaf(xv[i], wa.x, acc[i][0]);
                acc[i][1] = fmaf(xv[i], wa.y, acc[i][1]);
                acc[i][2] = fmaf(xv[i], wa.z, acc[i][2]);
                acc[i][3] = fmaf(xv[i], wa.w, acc[i][3]);
                acc[i][4] = fmaf(xv[i], wb.x, acc[i][4]);
                acc[i][5] = fmaf(xv[i], wb.y, acc[i][5]);
                acc[i][6] = fmaf(xv[i], wb.z, acc[i][6]);
                acc[i][7] = fmaf(xv[i], wb.w, acc[i][7]);
            }
        }

        // ---- Bias + ReLU + Layer 2 (128->2) + lane reduction ----
        #pragma unroll
        for (int i = 0; i < 4; ++i) {
            float s0 = 0.f, s1 = 0.f;
            #pragma unroll
            for (int j = 0; j < 8; ++j) {
                const float v = fmaxf(acc[i][j] + b1r[j], 0.f);
                s0 = fmaf(v, w2a[j], s0);
                s1 = fmaf(v, w2b[j], s1);
            }
            #pragma unroll
            for (int off = 1; off < 16; off <<= 1) {
                s0 += __shfl_xor(s0, off, 64);
                s1 += __shfl_xor(s1, off, 64);
            }
            if (tc == 0) {
                const int eg = tile * BE + e0 + i;
                if (eg < E) {
                    const float2 o = make_float2(s0 + bb0, s1 + bb1);
                    *reinterpret_cast<float2*>(&out[(size_t)eg * 2]) = o;
                }
            }
        }
    }
}

extern "C" void kernel_launch(void* const* d_in, const int* in_sizes, int n_in,
                              void* d_out, int out_size, void* d_ws, size_t ws_size,
                              hipStream_t stream)
{
    const float* h  = (const float*)d_in[0];
    const int*   ei = (const int*)d_in[1];
    const float* W1 = (const float*)d_in[2];
    const float* b1 = (const float*)d_in[3];
    const float* W2 = (const float*)d_in[4];
    const float* b2 = (const float*)d_in[5];
    float* out = (float*)d_out;

    const int E      = in_sizes[1] / 2;
    const int nTiles = (E + BE - 1) / BE;

    hipLaunchKernelGGL(edge_mlp_f32, dim3(256), dim3(256), 0, stream,
                       h, ei, W1, b1, W2, b2, out, E, nTiles);
}

// Round 2
// 123.574 us; speedup vs baseline: 5.9584x; 5.9584x over previous
//
#include <hip/hip_runtime.h>
#include <cstdint>

// EdgeMLP via bf16 MFMA: out[e] = relu(concat(h[src],h[dst]) @ W1 + b1) @ W2 + b2
// Per wave: 16 edges. A-fragments gathered straight from global (no LDS at all).
// W1 held register-resident as bf16 B-fragments (8 ntile x 4 kstep x 8 bf16).

constexpr int EMB = 64;
constexpr int HID = 128;

typedef short s16x8 __attribute__((ext_vector_type(8)));
typedef float f32x4 __attribute__((ext_vector_type(4)));

__device__ __forceinline__ short f2bf(float x) {
    unsigned u = __float_as_uint(x);
    u = (u + 0x7fffu + ((u >> 16) & 1u)) >> 16;   // round-to-nearest-even
    return (short)u;
}

__device__ __forceinline__ s16x8 load8f(const float* __restrict__ p) {
    float4 a = *reinterpret_cast<const float4*>(p);
    float4 b = *reinterpret_cast<const float4*>(p + 4);
    s16x8 f;
    f[0] = f2bf(a.x); f[1] = f2bf(a.y); f[2] = f2bf(a.z); f[3] = f2bf(a.w);
    f[4] = f2bf(b.x); f[5] = f2bf(b.y); f[6] = f2bf(b.z); f[7] = f2bf(b.w);
    return f;
}

// ---- prep: h fp32 -> bf16 into workspace (halves gather traffic) ----
__global__ void conv_h_kernel(const float* __restrict__ h,
                              unsigned short* __restrict__ hb, int n8) {
    const int i = blockIdx.x * blockDim.x + threadIdx.x;
    if (i >= n8) return;
    const float* p = h + (size_t)i * 8;
    float4 a = *reinterpret_cast<const float4*>(p);
    float4 b = *reinterpret_cast<const float4*>(p + 4);
    unsigned short r[8];
    r[0] = (unsigned short)f2bf(a.x); r[1] = (unsigned short)f2bf(a.y);
    r[2] = (unsigned short)f2bf(a.z); r[3] = (unsigned short)f2bf(a.w);
    r[4] = (unsigned short)f2bf(b.x); r[5] = (unsigned short)f2bf(b.y);
    r[6] = (unsigned short)f2bf(b.z); r[7] = (unsigned short)f2bf(b.w);
    *reinterpret_cast<uint4*>(hb + (size_t)i * 8) = *reinterpret_cast<const uint4*>(r);
}

template<bool BF16H>
__global__ __launch_bounds__(256, 2)
void edge_mlp_mfma(const float* __restrict__ h,
                   const unsigned short* __restrict__ hb,
                   const int* __restrict__ eidx,
                   const float* __restrict__ W1, const float* __restrict__ b1,
                   const float* __restrict__ W2, const float* __restrict__ b2,
                   float* __restrict__ out, int E, int nTiles)
{
    const int t    = threadIdx.x;
    const int wid  = t >> 6;
    const int lane = t & 63;
    const int tc   = lane & 15;   // A row (edge m) / B-C col (hidden n)
    const int bq   = lane >> 4;   // k-group

    // ---- W1 -> register-resident bf16 B-fragments (one-time, per wave) ----
    // B[k][n]: lane holds n = nt*16 + tc, k = ks*32 + bq*8 + j (j=0..7)
    s16x8 bfrag[8][4];
    #pragma unroll
    for (int nt = 0; nt < 8; ++nt) {
        const int n = nt * 16 + tc;
        #pragma unroll
        for (int ks = 0; ks < 4; ++ks) {
            const int kb = ks * 32 + bq * 8;
            s16x8 f;
            #pragma unroll
            for (int j = 0; j < 8; ++j) f[j] = f2bf(W1[(size_t)(kb + j) * HID + n]);
            bfrag[nt][ks] = f;
        }
    }

    // epilogue constants: per lane, the 8 hidden cols n = nt*16 + tc
    float b1r[8], w2a[8], w2b[8];
    #pragma unroll
    for (int nt = 0; nt < 8; ++nt) {
        const int n = nt * 16 + tc;
        b1r[nt] = b1[n];
        w2a[nt] = W2[n * 2 + 0];
        w2b[nt] = W2[n * 2 + 1];
    }
    const float bb0 = b2[0], bb1 = b2[1];

    const int waveStride = gridDim.x * 4;
    for (int tile = blockIdx.x * 4 + wid; tile < nTiles; tile += waveStride) {
        const int e  = tile * 16 + tc;
        const bool ok = (e < E);
        const int src = ok ? eidx[e]     : 0;
        const int dst = ok ? eidx[E + e] : 0;

        // A fragment: row m = tc, k = ks*32 + bq*8 + j. k<64 -> h[src], else h[dst].
        s16x8 afrag[4];
        if (BF16H) {
            const unsigned short* ps = hb + (size_t)src * EMB + bq * 8;
            const unsigned short* pd = hb + (size_t)dst * EMB + bq * 8;
            afrag[0] = *reinterpret_cast<const s16x8*>(ps);
            afrag[1] = *reinterpret_cast<const s16x8*>(ps + 32);
            afrag[2] = *reinterpret_cast<const s16x8*>(pd);
            afrag[3] = *reinterpret_cast<const s16x8*>(pd + 32);
        } else {
            const float* ps = h + (size_t)src * EMB + bq * 8;
            const float* pd = h + (size_t)dst * EMB + bq * 8;
            afrag[0] = load8f(ps);
            afrag[1] = load8f(ps + 32);
            afrag[2] = load8f(pd);
            afrag[3] = load8f(pd + 32);
        }

        f32x4 acc[8];
        #pragma unroll
        for (int nt = 0; nt < 8; ++nt) acc[nt] = f32x4{0.f, 0.f, 0.f, 0.f};

        #pragma unroll
        for (int ks = 0; ks < 4; ++ks) {
            #pragma unroll
            for (int nt = 0; nt < 8; ++nt)
                acc[nt] = __builtin_amdgcn_mfma_f32_16x16x32_bf16(
                              afrag[ks], bfrag[nt][ks], acc[nt], 0, 0, 0);
        }

        // ---- bias + ReLU + (128->2) + reduce over the 16 n-lanes ----
        // C layout: col n = nt*16 + tc, row m = bq*4 + r
        #pragma unroll
        for (int r = 0; r < 4; ++r) {
            float s0 = 0.f, s1 = 0.f;
            #pragma unroll
            for (int nt = 0; nt < 8; ++nt) {
                const float v = fmaxf(acc[nt][r] + b1r[nt], 0.f);
                s0 = fmaf(v, w2a[nt], s0);
                s1 = fmaf(v, w2b[nt], s1);
            }
            #pragma unroll
            for (int off = 1; off < 16; off <<= 1) {
                s0 += __shfl_xor(s0, off, 64);
                s1 += __shfl_xor(s1, off, 64);
            }
            if (tc == 0) {
                const int eo = tile * 16 + bq * 4 + r;
                if (eo < E)
                    *reinterpret_cast<float2*>(out + (size_t)eo * 2) =
                        make_float2(s0 + bb0, s1 + bb1);
            }
        }
    }
}

extern "C" void kernel_launch(void* const* d_in, const int* in_sizes, int n_in,
                              void* d_out, int out_size, void* d_ws, size_t ws_size,
                              hipStream_t stream)
{
    const float* h  = (const float*)d_in[0];
    const int*   ei = (const int*)d_in[1];
    const float* W1 = (const float*)d_in[2];
    const float* b1 = (const float*)d_in[3];
    const float* W2 = (const float*)d_in[4];
    const float* b2 = (const float*)d_in[5];
    float* out = (float*)d_out;

    const int nNodes = in_sizes[0] / EMB;
    const int E      = in_sizes[1] / 2;
    const int nTiles = (E + 15) / 16;
    const size_t hbBytes = (size_t)nNodes * EMB * sizeof(unsigned short);

    const int grid = 2048;

    if (ws_size >= hbBytes) {
        unsigned short* hb = (unsigned short*)d_ws;
        const int n8 = (nNodes * EMB) / 8;
        hipLaunchKernelGGL(conv_h_kernel, dim3((n8 + 255) / 256), dim3(256), 0, stream,
                           h, hb, n8);
        hipLaunchKernelGGL((edge_mlp_mfma<true>), dim3(grid), dim3(256), 0, stream,
                           h, hb, ei, W1, b1, W2, b2, out, E, nTiles);
    } else {
        hipLaunchKernelGGL((edge_mlp_mfma<false>), dim3(grid), dim3(256), 0, stream,
                           h, (const unsigned short*)nullptr, ei, W1, b1, W2, b2, out,
                           E, nTiles);
    }
}